// Round 1
// baseline (591.313 us; speedup 1.0000x reference)
//
#include <hip/hip_runtime.h>

#define TLEN 2048
#define T2   4096
#define H2   2048
#define CTOT 512
#define NMODE 4
#define MTOT (CTOT * H2)   // 1048576 bins total per mode

// ---------------- transpose x:(B,T,C)->(c=b*64+ch, t) ----------------
__global__ void k_transpose_in(const float* __restrict__ x, float* __restrict__ xr){
  __shared__ float tile[64][65];
  int blk = blockIdx.x;
  int b  = blk >> 5;            // 8 batches
  int t0 = (blk & 31) << 6;     // 32 t-tiles of 64
  int lo = threadIdx.x & 63;
  int r0 = threadIdx.x >> 6;    // 0..3
  for (int pass = 0; pass < 16; ++pass){
    int tt = r0 + (pass << 2);
    tile[tt][lo] = x[((size_t)(b * TLEN + t0 + tt)) * 64 + lo];  // lo = ch, coalesced
  }
  __syncthreads();
  for (int pass = 0; pass < 16; ++pass){
    int c2 = r0 + (pass << 2);
    xr[((size_t)(b * 64 + c2)) * TLEN + t0 + lo] = tile[lo][c2]; // lo = t, coalesced
  }
}

// ---------------- forward FFT: mirror-extend + 4096pt, keep bins 0..2047 ----------------
__global__ void k_fft_fwd(const float* __restrict__ xr, float2* __restrict__ F){
  __shared__ float2 bufA[T2];
  __shared__ float2 bufB[T2];
  int c = blockIdx.x;
  const float* f = xr + (size_t)c * TLEN;
  for (int i = threadIdx.x; i < T2; i += blockDim.x){
    int s = (i < 1024) ? (1023 - i) : ((i < 3072) ? (i - 1024) : (5119 - i));
    bufA[i] = make_float2(f[s], 0.0f);
  }
  __syncthreads();
  float2 *src = bufA, *dst = bufB;
  int n = T2, ls = 0;
  for (int st = 0; st < 12; ++st){
    int m = n >> 1;
    int smask = (1 << ls) - 1;
    for (int idx = threadIdx.x; idx < H2; idx += blockDim.x){
      int p = idx >> ls;
      int q = idx & smask;
      float2 a = src[q + (p << ls)];
      float2 b = src[q + ((p + m) << ls)];
      float sx = a.x + b.x, sy = a.y + b.y;
      float dx = a.x - b.x, dy = a.y - b.y;
      float ang = -6.283185307179586f * (float)p / (float)n;  // forward: e^{-i2pi p/n}
      float cw = cosf(ang), sw = sinf(ang);
      dst[q + ((2 * p) << ls)]     = make_float2(sx, sy);
      dst[q + ((2 * p + 1) << ls)] = make_float2(dx * cw - dy * sw, dx * sw + dy * cw);
    }
    __syncthreads();
    float2* t = src; src = dst; dst = t;
    n >>= 1; ++ls;
  }
  float2* out = F + (size_t)c * H2;
  for (int j = threadIdx.x; j < H2; j += blockDim.x) out[j] = src[j];
}

// ---------------- init accumulators / omega / convergence flags ----------------
__global__ void k_init(double* __restrict__ omega, double* __restrict__ accs,
                       int* __restrict__ conv){
  int t = threadIdx.x;
  if (t < 4)  omega[t] = 0.125 * (double)t;   // 0.5/K * k
  if (t < 45) accs[t]  = 0.0;                 // 5 iters * 4 modes * {fp,p} + 5 udiff
  if (t < 6)  conv[t]  = 0;
}

// ---------------- one mode update (per iteration) ----------------
__launch_bounds__(256)
__global__ void k_update(float2* __restrict__ u, const float2* __restrict__ F,
                         double* __restrict__ aFP, double* __restrict__ aP,
                         double* __restrict__ aD,
                         const double* __restrict__ omega, int k,
                         const int* __restrict__ convPrev){
  if (convPrev[0]) return;  // uniform early-exit: iteration converged
  const int base = blockIdx.x * H2;   // one channel per block
  const float om = (float)omega[k];
  double sfp = 0.0, sp = 0.0, sd = 0.0;
  for (int pp = 0; pp < 8; ++pp){
    int j = threadIdx.x + (pp << 8);
    int g = base + j;
    float2 fv = F[g];
    float2 u0 = u[g];
    float2 u1 = u[MTOT + g];
    float2 u2 = u[2 * MTOT + g];
    float2 u3 = u[3 * MTOT + g];
    float2 uo = (k == 0) ? u0 : ((k == 1) ? u1 : ((k == 2) ? u2 : u3));
    float ox = u0.x + u1.x + u2.x + u3.x - uo.x;
    float oy = u0.y + u1.y + u2.y + u3.y - uo.y;
    float fj = (float)j * (1.0f / 4096.0f);
    float dfr = fj - om;
    float denom = 1.0f + 2000.0f * dfr * dfr;
    float nx = (fv.x - ox) / denom;
    float ny = (fv.y - oy) / denom;
    u[k * MTOT + g] = make_float2(nx, ny);
    float pw = nx * nx + ny * ny;
    sfp += (double)(fj * pw);
    sp  += (double)pw;
    float ddx = nx - uo.x, ddy = ny - uo.y;
    sd  += (double)(ddx * ddx + ddy * ddy);
  }
  for (int off = 32; off > 0; off >>= 1){
    sfp += __shfl_down(sfp, off);
    sp  += __shfl_down(sp,  off);
    sd  += __shfl_down(sd,  off);
  }
  __shared__ double red[3][4];
  int wave = threadIdx.x >> 6;
  int lane = threadIdx.x & 63;
  if (lane == 0){ red[0][wave] = sfp; red[1][wave] = sp; red[2][wave] = sd; }
  __syncthreads();
  if (threadIdx.x == 0){
    double a = red[0][0] + red[0][1] + red[0][2] + red[0][3];
    double b = red[1][0] + red[1][1] + red[1][2] + red[1][3];
    double d = red[2][0] + red[2][1] + red[2][2] + red[2][3];
    atomicAdd(aFP, a); atomicAdd(aP, b); atomicAdd(aD, d);
  }
}

// ---------------- finalize: omega update + convergence check ----------------
__global__ void k_finalize(const double* __restrict__ aFP, const double* __restrict__ aP,
                           const double* __restrict__ aD,
                           double* __restrict__ omega, int k,
                           const int* __restrict__ convPrev, int* __restrict__ convNext,
                           int isLast){
  if (convPrev[0]){ if (isLast) convNext[0] = 1; return; }
  omega[k] = aFP[0] / aP[0];
  if (isLast){
    double ud = aD[0] / 4096.0 + 1.1920928955078125e-07;
    convNext[0] = (ud <= 5e-5) ? 1 : 0;
  }
}

// ---------------- inverse FFT of mode 0 with reference's Hermitian build ----------------
__global__ void k_ifft(const float2* __restrict__ u0, float* __restrict__ xl_s){
  __shared__ float2 bufA[T2];
  __shared__ float2 bufB[T2];
  int c = blockIdx.x;
  const float2* U = u0 + (size_t)c * H2;
  for (int j = threadIdx.x; j < H2; j += blockDim.x){
    float2 v = U[j];
    if (j == 0){
      bufA[0] = make_float2(v.x, -v.y);          // S[0] = conj(U[0])
    } else {
      bufA[j]      = v;                          // S[j] = U[j]
      bufA[T2 - j] = make_float2(v.x, -v.y);     // S[4096-j] = conj(U[j])
    }
  }
  if (threadIdx.x == 0){
    float2 v = U[H2 - 1];
    bufA[H2] = make_float2(v.x, -v.y);           // S[2048] = conj(U[2047]) (ref quirk)
  }
  __syncthreads();
  float2 *src = bufA, *dst = bufB;
  int n = T2, ls = 0;
  for (int st = 0; st < 12; ++st){
    int m = n >> 1;
    int smask = (1 << ls) - 1;
    for (int idx = threadIdx.x; idx < H2; idx += blockDim.x){
      int p = idx >> ls;
      int q = idx & smask;
      float2 a = src[q + (p << ls)];
      float2 b = src[q + ((p + m) << ls)];
      float sx = a.x + b.x, sy = a.y + b.y;
      float dx = a.x - b.x, dy = a.y - b.y;
      float ang = 6.283185307179586f * (float)p / (float)n;  // inverse: e^{+i2pi p/n}
      float cw = cosf(ang), sw = sinf(ang);
      dst[q + ((2 * p) << ls)]     = make_float2(sx, sy);
      dst[q + ((2 * p + 1) << ls)] = make_float2(dx * cw - dy * sw, dx * sw + dy * cw);
    }
    __syncthreads();
    float2* t = src; src = dst; dst = t;
    n >>= 1; ++ls;
  }
  const float scale = 1.0f / (float)T2;
  for (int t = threadIdx.x; t < TLEN; t += blockDim.x)
    xl_s[(size_t)c * TLEN + t] = src[1024 + t].x * scale;   // center slice, real part
}

// ---------------- transpose back + x_h = x - x_l ----------------
__global__ void k_transpose_out(const float* __restrict__ x, const float* __restrict__ xl_s,
                                float* __restrict__ xh, float* __restrict__ xl){
  __shared__ float tile[64][65];
  int blk = blockIdx.x;
  int b  = blk >> 5;
  int t0 = (blk & 31) << 6;
  int lo = threadIdx.x & 63;
  int r0 = threadIdx.x >> 6;
  for (int pass = 0; pass < 16; ++pass){
    int c2 = r0 + (pass << 2);
    tile[c2][lo] = xl_s[((size_t)(b * 64 + c2)) * TLEN + t0 + lo];  // lo = t, coalesced
  }
  __syncthreads();
  for (int pass = 0; pass < 16; ++pass){
    int tt = r0 + (pass << 2);
    size_t oi = ((size_t)(b * TLEN + t0 + tt)) * 64 + lo;           // lo = ch, coalesced
    float xlv = tile[lo][tt];
    float xv  = x[oi];
    xh[oi] = xv - xlv;
    xl[oi] = xlv;
  }
}

extern "C" void kernel_launch(void* const* d_in, const int* in_sizes, int n_in,
                              void* d_out, int out_size, void* d_ws, size_t ws_size,
                              hipStream_t stream){
  const float* x = (const float*)d_in[0];
  float* out_xh = (float*)d_out;
  float* out_xl = out_xh + (size_t)8 * TLEN * 64;

  char* ws = (char*)d_ws;
  float2* F    = (float2*)ws;                                 // 8 MB
  float2* u    = (float2*)(ws + (size_t)MTOT * 8);            // 32 MB (4 modes)
  float*  xr   = (float*)u;                                   // alias: used before u memset
  float*  xl_s = (float*)(ws + (size_t)MTOT * 8 * 2);         // alias u[1]: ifft reads only u[0]
  char* accbase = ws + (size_t)MTOT * 8 * 5;                  // ~41.9 MB offset
  double* omega = (double*)accbase;
  double* accs  = (double*)(accbase + 64);
  int*    conv  = (int*)(accbase + 64 + 512);

  k_transpose_in<<<256, 256, 0, stream>>>(x, xr);
  k_fft_fwd<<<CTOT, 256, 0, stream>>>(xr, F);
  hipMemsetAsync(u, 0, (size_t)NMODE * MTOT * 8, stream);     // after fft (stream-ordered)
  k_init<<<1, 64, 0, stream>>>(omega, accs, conv);

  for (int it = 0; it < 5; ++it){
    for (int k = 0; k < NMODE; ++k){
      double* aFP = accs + (size_t)(it * 4 + k) * 2;
      double* aP  = aFP + 1;
      double* aD  = accs + 40 + it;
      k_update<<<CTOT, 256, 0, stream>>>(u, F, aFP, aP, aD, omega, k, conv + it);
      k_finalize<<<1, 1, 0, stream>>>(aFP, aP, aD, omega, k, conv + it, conv + it + 1,
                                      (k == 3) ? 1 : 0);
    }
  }

  k_ifft<<<CTOT, 256, 0, stream>>>(u, xl_s);
  k_transpose_out<<<256, 256, 0, stream>>>(x, xl_s, out_xh, out_xl);
}

// Round 3
// 168.589 us; speedup vs baseline: 3.5074x; 3.5074x over previous
//
#include <hip/hip_runtime.h>
#include <math.h>

#define TLEN 2048
#define T2   4096
#define H2   2048
#define CTOT 512
#define MTOT (CTOT * H2)
#define EPS32 1.1920928955078125e-07

// ---- twiddle table e^{-i 2pi p/4096}, p in [0,2048), fp64-accurate; zero accs ----
__global__ void k_twiddle(float2* __restrict__ tw, double* __restrict__ accs){
  int p = blockIdx.x * 256 + threadIdx.x;
  double a = -6.283185307179586 * (double)p / 4096.0;
  tw[p] = make_float2((float)cos(a), (float)sin(a));
  if (blockIdx.x == 0 && threadIdx.x < 40) accs[threadIdx.x] = 0.0;
}

// ---- 12-stage Stockham FFT over bufA/bufB; result lands in bufA.
// sgn=+1: forward (table as-is, e^{-i...}); sgn=-1: inverse (conjugate table).
__device__ __forceinline__ void fft_stages(float2* bufA, float2* bufB,
                                           const float2* __restrict__ tw, float sgn){
  float2* src = bufA; float2* dst = bufB;
  const int tid = threadIdx.x;
  for (int st = 0; st < 12; ++st){
    int smask = (1 << st) - 1;
    for (int pp = 0; pp < 8; ++pp){
      int idx = tid + (pp << 8);
      int p = idx >> st;
      int q = idx & smask;
      float2 a = src[idx];            // src[q + (p<<st)]
      float2 b = src[idx + H2];       // src[q + ((p+m)<<st)]
      float2 w = tw[p << st];
      float wy = sgn * w.y;
      float sx = a.x + b.x, sy = a.y + b.y;
      float dx = a.x - b.x, dy = a.y - b.y;
      dst[q + ((2 * p) << st)]     = make_float2(sx, sy);
      dst[q + ((2 * p + 1) << st)] = make_float2(dx * w.x - dy * wy, dx * wy + dy * w.x);
    }
    __syncthreads();
    float2* t = src; src = dst; dst = t;
  }
}

// ---- block-reduce 9 doubles and atomically add into accs[0..8] ----
__device__ __forceinline__ void reduce9(double* acc, double* red, double* accs){
  const int tid = threadIdx.x, wave = tid >> 6, lane = tid & 63;
  #pragma unroll
  for (int i = 0; i < 9; ++i){
    double v = acc[i];
    for (int off = 32; off; off >>= 1) v += __shfl_down(v, off);
    if (lane == 0) red[i * 4 + wave] = v;
  }
  __syncthreads();
  if (tid < 9)
    atomicAdd(&accs[tid], red[tid*4+0] + red[tid*4+1] + red[tid*4+2] + red[tid*4+3]);
}

// ---- per-bin 4-mode Gauss-Seidel update chain ----
__device__ __forceinline__ void vmd_bin(float Fx, float Fy, float fj,
                                        const float* om, float* ux, float* uy,
                                        double* aFP, double* aP, double& aD){
  float sx = ux[0] + ux[1] + ux[2] + ux[3];
  float sy = uy[0] + uy[1] + uy[2] + uy[3];
  #pragma unroll
  for (int k = 0; k < 4; ++k){
    float ox = sx - ux[k], oy = sy - uy[k];
    float d = fj - om[k];
    float den = 1.0f + 2000.0f * d * d;
    float nx = (Fx - ox) / den, ny = (Fy - oy) / den;
    float pw = nx * nx + ny * ny;
    aFP[k] += (double)(fj * pw);
    aP[k]  += (double)pw;
    float ddx = nx - ux[k], ddy = ny - uy[k];
    aD += (double)(ddx * ddx + ddy * ddy);
    ux[k] = nx; uy[k] = ny;
    sx = ox + nx; sy = oy + ny;
  }
}

// ---- forward FFT (transpose fused, strided reads) + reference-iteration 1 ----
__launch_bounds__(256)
__global__ void k_fft_it1(const float* __restrict__ x, float2* __restrict__ F,
                          float2* __restrict__ u0, float2* __restrict__ u1,
                          float2* __restrict__ u2, float2* __restrict__ u3,
                          const float2* __restrict__ tw, double* __restrict__ accs){
  __shared__ float2 bufA[T2];
  __shared__ float2 bufB[T2];
  const int tid = threadIdx.x;
  const int c = blockIdx.x;
  const int b = c >> 6, ch = c & 63;
  const float* xb = x + ((size_t)b * TLEN) * 64 + ch;
  for (int pp = 0; pp < 16; ++pp){
    int i = tid + (pp << 8);
    int s = (i < 1024) ? (1023 - i) : ((i < 3072) ? (i - 1024) : (5119 - i));
    bufA[i] = make_float2(xb[(size_t)s * 64], 0.0f);
  }
  __syncthreads();
  fft_stages(bufA, bufB, tw, 1.0f);
  // positive-half spectrum in bufA[0..2047]; bufB is free scratch
  const float om[4] = {0.0f, 0.125f, 0.25f, 0.375f};
  double aFP[4] = {0,0,0,0}, aP[4] = {0,0,0,0}, aD = 0.0;
  const size_t base = (size_t)c * H2;
  for (int pp = 0; pp < 8; ++pp){
    int j = tid + (pp << 8);
    float2 Fv = bufA[j];
    F[base + j] = Fv;
    float fj = (float)j * (1.0f / 4096.0f);
    float ux[4] = {0.f,0.f,0.f,0.f}, uy[4] = {0.f,0.f,0.f,0.f};
    vmd_bin(Fv.x, Fv.y, fj, om, ux, uy, aFP, aP, aD);
    u0[base + j] = make_float2(ux[0], uy[0]);
    u1[base + j] = make_float2(ux[1], uy[1]);
    u2[base + j] = make_float2(ux[2], uy[2]);
    u3[base + j] = make_float2(ux[3], uy[3]);
  }
  double acc[9] = {aFP[0],aFP[1],aFP[2],aFP[3],aP[0],aP[1],aP[2],aP[3],aD};
  reduce9(acc, (double*)bufB, accs);
}

// ---- one full reference iteration (modes 0..3), guarded by prior convergence ----
__launch_bounds__(256)
__global__ void k_update(const float2* __restrict__ F,
                         float2* __restrict__ u0, float2* __restrict__ u1,
                         float2* __restrict__ u2, float2* __restrict__ u3,
                         const double* __restrict__ aPrev, double* __restrict__ aNext){
  __shared__ double red[36];
  if (aPrev[4] == 0.0) return;                                  // prev iter never ran
  if (aPrev[8] * (1.0 / 4096.0) + EPS32 <= 5e-5) return;        // converged
  float om[4];
  #pragma unroll
  for (int k = 0; k < 4; ++k) om[k] = (float)(aPrev[k] / aPrev[4 + k]);
  const int tid = threadIdx.x;
  const size_t base = (size_t)blockIdx.x * H2;
  const float4* F4 = (const float4*)(F + base);
  float4* u04 = (float4*)(u0 + base);
  float4* u14 = (float4*)(u1 + base);
  float4* u24 = (float4*)(u2 + base);
  float4* u34 = (float4*)(u3 + base);
  double aFP[4] = {0,0,0,0}, aP[4] = {0,0,0,0}, aD = 0.0;
  for (int pp = 0; pp < 4; ++pp){
    int m = tid + (pp << 8);              // float4 index: bins 2m, 2m+1
    float4 fv = F4[m];
    float4 a0 = u04[m], a1 = u14[m], a2 = u24[m], a3 = u34[m];
    {
      float ux[4] = {a0.x, a1.x, a2.x, a3.x};
      float uy[4] = {a0.y, a1.y, a2.y, a3.y};
      float fj = (float)(2 * m) * (1.0f / 4096.0f);
      vmd_bin(fv.x, fv.y, fj, om, ux, uy, aFP, aP, aD);
      a0.x = ux[0]; a0.y = uy[0]; a1.x = ux[1]; a1.y = uy[1];
      a2.x = ux[2]; a2.y = uy[2]; a3.x = ux[3]; a3.y = uy[3];
    }
    {
      float ux[4] = {a0.z, a1.z, a2.z, a3.z};
      float uy[4] = {a0.w, a1.w, a2.w, a3.w};
      float fj = (float)(2 * m + 1) * (1.0f / 4096.0f);
      vmd_bin(fv.z, fv.w, fj, om, ux, uy, aFP, aP, aD);
      a0.z = ux[0]; a0.w = uy[0]; a1.z = ux[1]; a1.w = uy[1];
      a2.z = ux[2]; a2.w = uy[2]; a3.z = ux[3]; a3.w = uy[3];
    }
    u04[m] = a0; u14[m] = a1; u24[m] = a2; u34[m] = a3;
  }
  double acc[9] = {aFP[0],aFP[1],aFP[2],aFP[3],aP[0],aP[1],aP[2],aP[3],aD};
  reduce9(acc, red, aNext);
}

// ---- reference-iteration 5's u0 update (guarded) + Hermitian build + IFFT ----
__launch_bounds__(256)
__global__ void k_ifft_it5(const float2* __restrict__ F,
                           float2* __restrict__ u0, const float2* __restrict__ u1,
                           const float2* __restrict__ u2, const float2* __restrict__ u3,
                           const float2* __restrict__ tw, const double* __restrict__ aPrev){
  __shared__ float2 bufA[T2];
  __shared__ float2 bufB[T2];
  const int tid = threadIdx.x;
  const int c = blockIdx.x;
  const size_t base = (size_t)c * H2;
  bool act = (aPrev[4] != 0.0) && (aPrev[8] * (1.0 / 4096.0) + EPS32 > 5e-5);
  float om0 = act ? (float)(aPrev[0] / aPrev[4]) : 0.0f;
  for (int pp = 0; pp < 8; ++pp){
    int j = tid + (pp << 8);
    float2 v = u0[base + j];
    if (act){
      float2 Fv = F[base + j];
      float2 b1 = u1[base + j], b2 = u2[base + j], b3 = u3[base + j];
      float ox = b1.x + b2.x + b3.x, oy = b1.y + b2.y + b3.y;   // k=0 first: others old
      float fj = (float)j * (1.0f / 4096.0f);
      float d = fj - om0;
      float den = 1.0f + 2000.0f * d * d;
      v = make_float2((Fv.x - ox) / den, (Fv.y - oy) / den);
    }
    // reference's exact Hermitian quirks
    if (j == 0){
      bufA[0] = make_float2(v.x, -v.y);            // S[0] = conj(U[0])
    } else {
      bufA[j]      = v;                            // S[j] = U[j]
      bufA[T2 - j] = make_float2(v.x, -v.y);       // S[4096-j] = conj(U[j])
    }
    if (j == H2 - 1) bufA[H2] = make_float2(v.x, -v.y);  // S[2048] = conj(U[2047])
  }
  __syncthreads();
  fft_stages(bufA, bufB, tw, -1.0f);
  // write x_l into this block's own (already consumed) u0 slot: floats [c*4096 ..)
  float* xl = (float*)u0;
  const float scale = 1.0f / (float)T2;
  for (int pp = 0; pp < 8; ++pp){
    int t = tid + (pp << 8);
    xl[(size_t)c * T2 + t] = bufA[1024 + t].x * scale;
  }
}

// ---- transpose back + x_h = x - x_l (xl_s channel stride = 4096 floats) ----
__global__ void k_transpose_out(const float* __restrict__ x, const float* __restrict__ xl_s,
                                float* __restrict__ xh, float* __restrict__ xl){
  __shared__ float tile[64][65];
  int blk = blockIdx.x;
  int b  = blk >> 5;
  int t0 = (blk & 31) << 6;
  int lo = threadIdx.x & 63;
  int r0 = threadIdx.x >> 6;
  for (int pass = 0; pass < 16; ++pass){
    int c2 = r0 + (pass << 2);
    tile[c2][lo] = xl_s[((size_t)(b * 64 + c2)) * T2 + t0 + lo];  // lo = t, coalesced
  }
  __syncthreads();
  for (int pass = 0; pass < 16; ++pass){
    int tt = r0 + (pass << 2);
    size_t oi = ((size_t)(b * TLEN + t0 + tt)) * 64 + lo;         // lo = ch, coalesced
    float xlv = tile[lo][tt];
    float xv  = x[oi];
    xh[oi] = xv - xlv;
    xl[oi] = xlv;
  }
}

extern "C" void kernel_launch(void* const* d_in, const int* in_sizes, int n_in,
                              void* d_out, int out_size, void* d_ws, size_t ws_size,
                              hipStream_t stream){
  const float* x = (const float*)d_in[0];
  float* out_xh = (float*)d_out;
  float* out_xl = out_xh + (size_t)8 * TLEN * 64;

  char* ws = (char*)d_ws;
  float2* F  = (float2*)ws;                              // 8 MiB
  float2* u0 = (float2*)(ws + ((size_t)8  << 20));       // 8 MiB (later holds x_l)
  float2* u1 = (float2*)(ws + ((size_t)16 << 20));
  float2* u2 = (float2*)(ws + ((size_t)24 << 20));
  float2* u3 = (float2*)(ws + ((size_t)32 << 20));
  float2* tw = (float2*)(ws + ((size_t)40 << 20));       // 16 KiB
  double* accs = (double*)(ws + ((size_t)40 << 20) + 16384);  // 36 doubles (4 sets x 9)

  k_twiddle<<<8, 256, 0, stream>>>(tw, accs);
  k_fft_it1<<<CTOT, 256, 0, stream>>>(x, F, u0, u1, u2, u3, tw, accs);       // ref iter 1
  k_update<<<CTOT, 256, 0, stream>>>(F, u0, u1, u2, u3, accs,      accs + 9);  // iter 2
  k_update<<<CTOT, 256, 0, stream>>>(F, u0, u1, u2, u3, accs + 9,  accs + 18); // iter 3
  k_update<<<CTOT, 256, 0, stream>>>(F, u0, u1, u2, u3, accs + 18, accs + 27); // iter 4
  k_ifft_it5<<<CTOT, 256, 0, stream>>>(F, u0, u1, u2, u3, tw, accs + 27);    // iter 5 + ifft
  k_transpose_out<<<256, 256, 0, stream>>>(x, (const float*)u0, out_xh, out_xl);
}

// Round 4
// 154.943 us; speedup vs baseline: 3.8163x; 1.0881x over previous
//
#include <hip/hip_runtime.h>
#include <math.h>

#define TLEN 2048
#define T2   4096
#define H2   2048
#define CTOT 512
#define EPS32 1.1920928955078125e-07

typedef _Float16 half8 __attribute__((ext_vector_type(8)));
typedef _Float16 half4 __attribute__((ext_vector_type(4)));

// ---- prep: coalesced transpose x:(B,T,C)->(c,t), twiddle table, accs zero ----
__global__ void k_prep(const float* __restrict__ x, float* __restrict__ xr,
                       float2* __restrict__ tw, double* __restrict__ accs){
  const int blk = blockIdx.x, tid = threadIdx.x;
  if (blk < 8){                       // 2048 twiddles e^{-i 2pi p/4096}, fp64-accurate
    int p = (blk << 8) + tid;
    double a = -6.283185307179586 * (double)p / 4096.0;
    tw[p] = make_float2((float)cos(a), (float)sin(a));
  }
  if (blk == 8 && tid < 36) accs[tid] = 0.0;
  __shared__ float tile[64][65];
  const int b  = blk >> 5;            // 8 batches x 32 t-tiles
  const int t0 = (blk & 31) << 6;
  const int lo = tid & 63, r0 = tid >> 6;
  for (int pass = 0; pass < 16; ++pass){
    int tt = r0 + (pass << 2);
    tile[tt][lo] = x[((size_t)(b * TLEN + t0 + tt)) * 64 + lo];  // lo = ch, coalesced
  }
  __syncthreads();
  for (int pass = 0; pass < 16; ++pass){
    int c2 = r0 + (pass << 2);
    xr[((size_t)(b * 64 + c2)) * TLEN + t0 + lo] = tile[lo][c2]; // lo = t, coalesced
  }
}

// ---- 12-stage Stockham radix-2 FFT; result lands in bufA. sgn=+1 fwd, -1 inv ----
__device__ __forceinline__ void fft_stages(float2* bufA, float2* bufB,
                                           const float2* __restrict__ tw, float sgn){
  float2* src = bufA; float2* dst = bufB;
  const int tid = threadIdx.x;
  for (int st = 0; st < 12; ++st){
    int smask = (1 << st) - 1;
    for (int pp = 0; pp < 8; ++pp){
      int idx = tid + (pp << 8);
      int p = idx >> st;
      int q = idx & smask;
      float2 a = src[idx];
      float2 b = src[idx + H2];
      float2 w = tw[p << st];
      float wy = sgn * w.y;
      float sx = a.x + b.x, sy = a.y + b.y;
      float dx = a.x - b.x, dy = a.y - b.y;
      dst[q + ((2 * p) << st)]     = make_float2(sx, sy);
      dst[q + ((2 * p + 1) << st)] = make_float2(dx * w.x - dy * wy, dx * wy + dy * w.x);
    }
    __syncthreads();
    float2* t = src; src = dst; dst = t;
  }
}

// ---- block-reduce 9 doubles -> atomicAdd into accs[0..8] ----
__device__ __forceinline__ void reduce9(double* acc, double* red, double* accs){
  const int tid = threadIdx.x, wave = tid >> 6, lane = tid & 63;
  #pragma unroll
  for (int i = 0; i < 9; ++i){
    double v = acc[i];
    for (int off = 32; off; off >>= 1) v += __shfl_down(v, off);
    if (lane == 0) red[i * 4 + wave] = v;
  }
  __syncthreads();
  if (tid < 9)
    atomicAdd(&accs[tid], red[tid*4+0] + red[tid*4+1] + red[tid*4+2] + red[tid*4+3]);
}

// ---- per-bin 4-mode Gauss-Seidel chain, with stats ----
__device__ __forceinline__ void vmd_bin(float Fx, float Fy, float fj,
                                        const float* om, float* ux, float* uy,
                                        double* aFP, double* aP, double& aD){
  float sx = ux[0] + ux[1] + ux[2] + ux[3];
  float sy = uy[0] + uy[1] + uy[2] + uy[3];
  #pragma unroll
  for (int k = 0; k < 4; ++k){
    float ox = sx - ux[k], oy = sy - uy[k];
    float d = fj - om[k];
    float den = 1.0f + 2000.0f * d * d;
    float nx = (Fx - ox) / den, ny = (Fy - oy) / den;
    float pw = nx * nx + ny * ny;
    aFP[k] += (double)(fj * pw);
    aP[k]  += (double)pw;
    float ddx = nx - ux[k], ddy = ny - uy[k];
    aD += (double)(ddx * ddx + ddy * ddy);
    ux[k] = nx; uy[k] = ny;
    sx = ox + nx; sy = oy + ny;
  }
}

// ---- same chain, no stats (for the deterministic iter-1 recompute) ----
__device__ __forceinline__ void vmd_chain(float Fx, float Fy, float fj,
                                          const float* om, float* ux, float* uy){
  float sx = ux[0] + ux[1] + ux[2] + ux[3];
  float sy = uy[0] + uy[1] + uy[2] + uy[3];
  #pragma unroll
  for (int k = 0; k < 4; ++k){
    float ox = sx - ux[k], oy = sy - uy[k];
    float d = fj - om[k];
    float den = 1.0f + 2000.0f * d * d;
    float nx = (Fx - ox) / den, ny = (Fy - oy) / den;
    ux[k] = nx; uy[k] = ny;
    sx = ox + nx; sy = oy + ny;
  }
}

// ---- forward FFT (coalesced xr) + iter-1 stats only (u not stored) ----
__launch_bounds__(256)
__global__ void k_fft_it1(const float* __restrict__ xr, float2* __restrict__ F,
                          const float2* __restrict__ tw, double* __restrict__ accs){
  __shared__ float2 bufA[T2];
  __shared__ float2 bufB[T2];
  const int tid = threadIdx.x;
  const int c = blockIdx.x;
  const float* f = xr + (size_t)c * TLEN;
  for (int pp = 0; pp < 16; ++pp){
    int i = tid + (pp << 8);
    int s = (i < 1024) ? (1023 - i) : ((i < 3072) ? (i - 1024) : (5119 - i));
    bufA[i] = make_float2(f[s], 0.0f);
  }
  __syncthreads();
  fft_stages(bufA, bufB, tw, 1.0f);     // spectrum in bufA; bufB free scratch
  const float om[4] = {0.0f, 0.125f, 0.25f, 0.375f};
  double aFP[4] = {0,0,0,0}, aP[4] = {0,0,0,0}, aD = 0.0;
  const size_t base = (size_t)c * H2;
  for (int pp = 0; pp < 8; ++pp){
    int j = tid + (pp << 8);
    float2 Fv = bufA[j];
    F[base + j] = Fv;
    float fj = (float)j * (1.0f / 4096.0f);
    float ux[4] = {0.f,0.f,0.f,0.f}, uy[4] = {0.f,0.f,0.f,0.f};
    vmd_bin(Fv.x, Fv.y, fj, om, ux, uy, aFP, aP, aD);
  }
  double acc[9] = {aFP[0],aFP[1],aFP[2],aFP[3],aP[0],aP[1],aP[2],aP[3],aD};
  reduce9(acc, (double*)bufB, accs);
}

// ---- iter 2: recompute iter-1 u from F, then iter-2 chain; store fp16 AoS ----
__launch_bounds__(256)
__global__ void k_it2(const float2* __restrict__ F, half8* __restrict__ uall,
                      const double* __restrict__ a1, double* __restrict__ a2){
  __shared__ double red[36];
  const bool run2 = (a1[8] * (1.0 / 4096.0) + EPS32 > 5e-5);
  const float om1[4] = {0.0f, 0.125f, 0.25f, 0.375f};
  float om2[4] = {0,0,0,0};
  if (run2){
    #pragma unroll
    for (int k = 0; k < 4; ++k) om2[k] = (float)(a1[k] / a1[4 + k]);
  }
  const int tid = threadIdx.x;
  const size_t base = (size_t)blockIdx.x * H2;
  double aFP[4] = {0,0,0,0}, aP[4] = {0,0,0,0}, aD = 0.0;
  for (int pp = 0; pp < 8; ++pp){
    int j = tid + (pp << 8);
    size_t g = base + j;
    float2 Fv = F[g];
    float fj = (float)j * (1.0f / 4096.0f);
    float ux[4] = {0.f,0.f,0.f,0.f}, uy[4] = {0.f,0.f,0.f,0.f};
    vmd_chain(Fv.x, Fv.y, fj, om1, ux, uy);         // identical iter-1 values
    if (run2) vmd_bin(Fv.x, Fv.y, fj, om2, ux, uy, aFP, aP, aD);
    half8 h;
    h[0] = (_Float16)ux[0]; h[1] = (_Float16)uy[0];
    h[2] = (_Float16)ux[1]; h[3] = (_Float16)uy[1];
    h[4] = (_Float16)ux[2]; h[5] = (_Float16)uy[2];
    h[6] = (_Float16)ux[3]; h[7] = (_Float16)uy[3];
    uall[g] = h;
  }
  if (run2){
    double acc[9] = {aFP[0],aFP[1],aFP[2],aFP[3],aP[0],aP[1],aP[2],aP[3],aD};
    reduce9(acc, red, a2);
  }
}

// ---- iter 3: full chain on fp16 AoS state ----
__launch_bounds__(256)
__global__ void k_it3(const float2* __restrict__ F, half8* __restrict__ uall,
                      const double* __restrict__ aPrev, double* __restrict__ aNext){
  __shared__ double red[36];
  if (aPrev[4] == 0.0) return;
  if (aPrev[8] * (1.0 / 4096.0) + EPS32 <= 5e-5) return;
  float om[4];
  #pragma unroll
  for (int k = 0; k < 4; ++k) om[k] = (float)(aPrev[k] / aPrev[4 + k]);
  const int tid = threadIdx.x;
  const size_t base = (size_t)blockIdx.x * H2;
  double aFP[4] = {0,0,0,0}, aP[4] = {0,0,0,0}, aD = 0.0;
  for (int pp = 0; pp < 8; ++pp){
    int j = tid + (pp << 8);
    size_t g = base + j;
    float2 Fv = F[g];
    half8 h = uall[g];
    float ux[4] = {(float)h[0],(float)h[2],(float)h[4],(float)h[6]};
    float uy[4] = {(float)h[1],(float)h[3],(float)h[5],(float)h[7]};
    float fj = (float)j * (1.0f / 4096.0f);
    vmd_bin(Fv.x, Fv.y, fj, om, ux, uy, aFP, aP, aD);
    h[0] = (_Float16)ux[0]; h[1] = (_Float16)uy[0];
    h[2] = (_Float16)ux[1]; h[3] = (_Float16)uy[1];
    h[4] = (_Float16)ux[2]; h[5] = (_Float16)uy[2];
    h[6] = (_Float16)ux[3]; h[7] = (_Float16)uy[3];
    uall[g] = h;
  }
  double acc[9] = {aFP[0],aFP[1],aFP[2],aFP[3],aP[0],aP[1],aP[2],aP[3],aD};
  reduce9(acc, red, aNext);
}

// ---- iter 4: chain, but store only (u0, u1+u2+u3) — all the IFFT needs ----
__launch_bounds__(256)
__global__ void k_it4(const float2* __restrict__ F, const half8* __restrict__ uall,
                      half4* __restrict__ uo_s,
                      const double* __restrict__ aPrev, double* __restrict__ aNext){
  __shared__ double red[36];
  if (aPrev[4] == 0.0) return;
  if (aPrev[8] * (1.0 / 4096.0) + EPS32 <= 5e-5) return;
  float om[4];
  #pragma unroll
  for (int k = 0; k < 4; ++k) om[k] = (float)(aPrev[k] / aPrev[4 + k]);
  const int tid = threadIdx.x;
  const size_t base = (size_t)blockIdx.x * H2;
  double aFP[4] = {0,0,0,0}, aP[4] = {0,0,0,0}, aD = 0.0;
  for (int pp = 0; pp < 8; ++pp){
    int j = tid + (pp << 8);
    size_t g = base + j;
    float2 Fv = F[g];
    half8 h = uall[g];
    float ux[4] = {(float)h[0],(float)h[2],(float)h[4],(float)h[6]};
    float uy[4] = {(float)h[1],(float)h[3],(float)h[5],(float)h[7]};
    float fj = (float)j * (1.0f / 4096.0f);
    vmd_bin(Fv.x, Fv.y, fj, om, ux, uy, aFP, aP, aD);
    half4 o;
    o[0] = (_Float16)ux[0];                    o[1] = (_Float16)uy[0];
    o[2] = (_Float16)(ux[1] + ux[2] + ux[3]);  o[3] = (_Float16)(uy[1] + uy[2] + uy[3]);
    uo_s[g] = o;
  }
  double acc[9] = {aFP[0],aFP[1],aFP[2],aFP[3],aP[0],aP[1],aP[2],aP[3],aD};
  reduce9(acc, red, aNext);
}

// ---- iter-5 mode-0 update (guarded) + Hermitian build + inverse FFT ----
__launch_bounds__(256)
__global__ void k_ifft5(const float2* __restrict__ F, const half8* __restrict__ uall,
                        const half4* __restrict__ uo_s, const float2* __restrict__ tw,
                        const double* __restrict__ a4, float* __restrict__ xl_s){
  __shared__ float2 bufA[T2];
  __shared__ float2 bufB[T2];
  const int tid = threadIdx.x;
  const size_t base = (size_t)blockIdx.x * H2;
  const bool ran4 = (a4[4] != 0.0);
  const bool act = ran4 && (a4[8] * (1.0 / 4096.0) + EPS32 > 5e-5);
  const float om0 = act ? (float)(a4[0] / a4[4]) : 0.0f;
  for (int pp = 0; pp < 8; ++pp){
    int j = tid + (pp << 8);
    size_t g = base + j;
    float2 v;
    if (act){                         // u0^(5) = (F - sum_{k>0} u_k^(4)) / den
      half4 o = uo_s[g];
      float2 Fv = F[g];
      float fj = (float)j * (1.0f / 4096.0f);
      float d = fj - om0;
      float den = 1.0f + 2000.0f * d * d;
      v = make_float2((Fv.x - (float)o[2]) / den, (Fv.y - (float)o[3]) / den);
    } else if (ran4){
      half4 o = uo_s[g];
      v = make_float2((float)o[0], (float)o[1]);
    } else {                          // iter-4 never ran: last state is in uall
      half8 h = uall[g];
      v = make_float2((float)h[0], (float)h[1]);
    }
    if (j == 0){
      bufA[0] = make_float2(v.x, -v.y);            // S[0] = conj(U[0])
    } else {
      bufA[j]      = v;                            // S[j] = U[j]
      bufA[T2 - j] = make_float2(v.x, -v.y);       // S[4096-j] = conj(U[j])
    }
    if (j == H2 - 1) bufA[H2] = make_float2(v.x, -v.y);  // S[2048] = conj(U[2047])
  }
  __syncthreads();
  fft_stages(bufA, bufB, tw, -1.0f);
  const float scale = 1.0f / (float)T2;
  for (int pp = 0; pp < 8; ++pp){
    int t = tid + (pp << 8);
    xl_s[(size_t)blockIdx.x * TLEN + t] = bufA[1024 + t].x * scale;
  }
}

// ---- transpose back + x_h = x - x_l ----
__global__ void k_tout(const float* __restrict__ x, const float* __restrict__ xl_s,
                       float* __restrict__ xh, float* __restrict__ xl){
  __shared__ float tile[64][65];
  int blk = blockIdx.x;
  int b  = blk >> 5;
  int t0 = (blk & 31) << 6;
  int lo = threadIdx.x & 63;
  int r0 = threadIdx.x >> 6;
  for (int pass = 0; pass < 16; ++pass){
    int c2 = r0 + (pass << 2);
    tile[c2][lo] = xl_s[((size_t)(b * 64 + c2)) * TLEN + t0 + lo];
  }
  __syncthreads();
  for (int pass = 0; pass < 16; ++pass){
    int tt = r0 + (pass << 2);
    size_t oi = ((size_t)(b * TLEN + t0 + tt)) * 64 + lo;
    float xlv = tile[lo][tt];
    float xv  = x[oi];
    xh[oi] = xv - xlv;
    xl[oi] = xlv;
  }
}

extern "C" void kernel_launch(void* const* d_in, const int* in_sizes, int n_in,
                              void* d_out, int out_size, void* d_ws, size_t ws_size,
                              hipStream_t stream){
  const float* x = (const float*)d_in[0];
  float* out_xh = (float*)d_out;
  float* out_xl = out_xh + (size_t)8 * TLEN * 64;

  char* ws = (char*)d_ws;
  float2* F    = (float2*)ws;                             // 8 MiB
  half8*  uall = (half8*)(ws + ((size_t)8  << 20));       // 16 MiB (4 modes fp16 AoS)
  half4*  uo_s = (half4*)(ws + ((size_t)24 << 20));       // 8 MiB (u0, u1+u2+u3)
  float*  xr   = (float*)(ws + ((size_t)32 << 20));       // 4 MiB
  float*  xl_s = (float*)(ws + ((size_t)36 << 20));       // 4 MiB
  float2* tw   = (float2*)(ws + ((size_t)40 << 20));      // 16 KiB
  double* accs = (double*)(ws + ((size_t)40 << 20) + 16384); // 36 doubles

  k_prep<<<256, 256, 0, stream>>>(x, xr, tw, accs);
  k_fft_it1<<<CTOT, 256, 0, stream>>>(xr, F, tw, accs);                     // iter 1 stats
  k_it2<<<CTOT, 256, 0, stream>>>(F, uall, accs, accs + 9);                 // iter 2
  k_it3<<<CTOT, 256, 0, stream>>>(F, uall, accs + 9, accs + 18);            // iter 3
  k_it4<<<CTOT, 256, 0, stream>>>(F, uall, uo_s, accs + 18, accs + 27);     // iter 4
  k_ifft5<<<CTOT, 256, 0, stream>>>(F, uall, uo_s, tw, accs + 27, xl_s);    // iter 5 + ifft
  k_tout<<<256, 256, 0, stream>>>(x, xl_s, out_xh, out_xl);
}